// Round 4
// baseline (239.788 us; speedup 1.0000x reference)
//
#include <hip/hip_runtime.h>
#include <hip/hip_cooperative_groups.h>
#include <math.h>

namespace cg = cooperative_groups;

// Problem constants (fixed by reference setup_inputs)
#define B_SZ  64
#define N_IN  1024
#define IDIM  64
#define NC    16
#define DC    32
#define NQ    4       // blocks per batch
#define QROWS 256     // rows per block
#define NTHR  512

// Workspace (floats): cs[64][4][64] @0, sp1[64][4][16][64] @16384, sp2 @278528.
// Nothing needs zero-init (fully written before read).
#define WS_CS  0
#define WS_SP1 16384
#define WS_SP2 278528

__device__ __forceinline__ float rdlane_f(float v, int l) {
    return __int_as_float(__builtin_amdgcn_readlane(__float_as_int(v), l));
}

__global__ __launch_bounds__(NTHR, 2)
void k_fused(const float* __restrict__ x, const float* __restrict__ W,
             float* __restrict__ out, float* __restrict__ cs,
             float* __restrict__ sp1, float* __restrict__ sp2) {
    const int b = blockIdx.x >> 2, q = blockIdx.x & 3;
    const int tid = threadIdx.x, lane = tid & 63, wave = tid >> 6;

    // LDS: 64 + 4 + 2 + 16 = 86 KB -> 1 block/CU
    __shared__ float xT[IDIM * QROWS];   // skewed transpose: (n,i) at xT[i*256 + ((n+i)&255)]
    __shared__ float wvT[IDIM * NC];     // wv transposed [i][c] for float4 broadcast reads
    __shared__ float vSm[NC * DC];
    __shared__ float scr[4096];          // time-multiplexed: redSm / aSm / pSm (16 KB)

    cg::grid_group grid = cg::this_grid();

    // s = red @ W[c] (+scale), squash -> per-thread v for (c = tid>>5, d = tid&31)
    auto caps_v = [&](bool iter0) -> float {
        const int d = tid & 31, c = tid >> 5;
        const float* Wc = W + c * (IDIM * DC) + d;
        float s = 0.f;
        if (iter0) {
#pragma unroll 8
            for (int i = 0; i < IDIM; i++) s += scr[i] * Wc[i * DC];
            s *= (1.f / 16.f);
        } else {
#pragma unroll 8
            for (int i = 0; i < IDIM; i++) s += scr[c * 64 + i] * Wc[i * DC];
        }
        float n2 = s * s;
#pragma unroll
        for (int m = 16; m >= 1; m >>= 1) n2 += __shfl_xor(n2, m);  // within 32-lane half
        return (n2 / (1.f + n2)) * s / (sqrtf(n2) + 1e-8f);
    };

    // wvT[i][c] = sum_d W[c,i,d] * v[c,d]
    auto make_wv = [&]() {
        const int i = tid & 63, ch = tid >> 6;
#pragma unroll
        for (int h = 0; h < 2; h++) {
            const int c = ch + h * 8;
            const float4* Wr = reinterpret_cast<const float4*>(W + ((size_t)c * IDIM + i) * DC);
            float acc = 0.f;
#pragma unroll
            for (int dq = 0; dq < 8; dq++) {
                const float4 wq = Wr[dq];
                acc += wq.x * vSm[c * DC + dq * 4]     + wq.y * vSm[c * DC + dq * 4 + 1]
                     + wq.z * vSm[c * DC + dq * 4 + 2] + wq.w * vSm[c * DC + dq * 4 + 3];
            }
            wvT[i * NC + c] = acc;
        }
    };

    const int r = tid & 255, cb = tid >> 8;   // row, capsule-half (persistent mapping)
    float bl[8];                              // routing logits live in registers

    // one routing iteration: agreement -> (bl init/add) -> softmax -> xs partials -> sp
    auto route = [&](bool first, float* sp) {
        float a[8];
#pragma unroll
        for (int cc = 0; cc < 8; cc++) a[cc] = 0.f;
#pragma unroll
        for (int i = 0; i < IDIM; i++) {
            const float xv = xT[i * QROWS + ((r + i) & (QROWS - 1))];
            const float4 w0 = *reinterpret_cast<const float4*>(&wvT[i * NC + cb * 8]);
            const float4 w1 = *reinterpret_cast<const float4*>(&wvT[i * NC + cb * 8 + 4]);
            a[0] += xv * w0.x; a[1] += xv * w0.y; a[2] += xv * w0.z; a[3] += xv * w0.w;
            a[4] += xv * w1.x; a[5] += xv * w1.y; a[6] += xv * w1.z; a[7] += xv * w1.w;
        }
        if (first) {
#pragma unroll
            for (int cc = 0; cc < 8; cc++) bl[cc] = a[cc];
        } else {
#pragma unroll
            for (int cc = 0; cc < 8; cc++) a[cc] += bl[cc];
        }
        // softmax exchange: aSm[c][r] (conflict-free scalar, lanes have consecutive r)
#pragma unroll
        for (int cc = 0; cc < 8; cc++) scr[(cb * 8 + cc) * 256 + r] = a[cc];
        __syncthreads();
        float av[16];
#pragma unroll
        for (int k = 0; k < NC; k++) av[k] = scr[k * 256 + r];
        float mx = av[0];
#pragma unroll
        for (int k = 1; k < NC; k++) mx = fmaxf(mx, av[k]);
        float ssum = 0.f;
#pragma unroll
        for (int k = 0; k < NC; k++) { av[k] = __expf(av[k] - mx); ssum += av[k]; }
        const float inv = 1.f / ssum;
        float cw8[8];                 // compile-time indices in both arms (rule #20)
        if (cb == 0) {
#pragma unroll
            for (int cc = 0; cc < 8; cc++) cw8[cc] = av[cc] * inv;
        } else {
#pragma unroll
            for (int cc = 0; cc < 8; cc++) cw8[cc] = av[8 + cc] * inv;
        }
        __syncthreads();              // aSm reads done; scr becomes pSm

        // xs: wave w -> rows (w&3)*64..+64, caps cb*8..+8; lane = i.
        // cw for row np lives in lane nl of THIS wave -> v_readlane broadcast.
        float acc[8];
#pragma unroll
        for (int cc = 0; cc < 8; cc++) acc[cc] = 0.f;
        const int rbase = (wave & 3) * 64;
#pragma unroll
        for (int nl = 0; nl < 64; nl++) {
            const int np = rbase + nl;
            const float xv = xT[lane * QROWS + ((np + lane) & (QROWS - 1))];
#pragma unroll
            for (int cc = 0; cc < 8; cc++) acc[cc] += rdlane_f(cw8[cc], nl) * xv;
        }
#pragma unroll
        for (int cc = 0; cc < 8; cc++) scr[wave * 512 + cc * 64 + lane] = acc[cc];
        __syncthreads();
        // reduce 4 row-blocks per (c,i); write sp[b][q][c][i] coalesced
        float* spq = sp + (size_t)(b * NQ + q) * (NC * IDIM);
#pragma unroll
        for (int m = 0; m < 2; m++) {
            const int o = tid + m * 512;
            const int c = o >> 6, i2 = o & 63;
            const int base = (c >> 3) * 2048 + (c & 7) * 64 + i2;
            spq[o] = scr[base] + scr[base + 512] + scr[base + 1024] + scr[base + 1536];
        }
    };

    // ---- P0: load x slice (once!) into skewed-transposed LDS
    const float4* xb4 = reinterpret_cast<const float4*>(x + ((size_t)b * N_IN + q * QROWS) * IDIM);
#pragma unroll
    for (int m = 0; m < 8; m++) {
        const int f = tid + m * NTHR;
        const float4 v4 = xb4[f];
        const int np = f >> 4, i0 = (f & 15) * 4;
        xT[(i0 + 0) * QROWS + ((np + i0 + 0) & (QROWS - 1))] = v4.x;
        xT[(i0 + 1) * QROWS + ((np + i0 + 1) & (QROWS - 1))] = v4.y;
        xT[(i0 + 2) * QROWS + ((np + i0 + 2) & (QROWS - 1))] = v4.z;
        xT[(i0 + 3) * QROWS + ((np + i0 + 3) & (QROWS - 1))] = v4.w;
    }
    __syncthreads();
    // ---- colsum partial -> cs[b][q][i]
    {
        float s = 0.f;
#pragma unroll
        for (int t = 0; t < 32; t++) {
            const int np = wave * 32 + t;
            s += xT[lane * QROWS + ((np + lane) & (QROWS - 1))];
        }
        scr[wave * 64 + lane] = s;
    }
    __syncthreads();
    if (tid < 64) {
        float rr = 0.f;
#pragma unroll
        for (int w2 = 0; w2 < 8; w2++) rr += scr[w2 * 64 + tid];
        cs[(b * NQ + q) * 64 + tid] = rr;
    }
    __threadfence();
    grid.sync();

    // ---- iter-0 capsule: red[i] = sum_q cs
    if (tid < 64) {
        float rr = 0.f;
#pragma unroll
        for (int k = 0; k < NQ; k++) rr += cs[(b * NQ + k) * 64 + tid];
        scr[tid] = rr;
    }
    __syncthreads();
    vSm[(tid >> 5) * DC + (tid & 31)] = caps_v(true);
    __syncthreads();
    make_wv();
    __syncthreads();

    route(true, sp1);
    __threadfence();
    grid.sync();

    // ---- iter-1 capsule from sp1
#pragma unroll
    for (int m = 0; m < 2; m++) {
        const int o = tid + m * 512;
        float rr = 0.f;
#pragma unroll
        for (int k = 0; k < NQ; k++) rr += sp1[(size_t)(b * NQ + k) * (NC * IDIM) + o];
        scr[o] = rr;
    }
    __syncthreads();
    vSm[(tid >> 5) * DC + (tid & 31)] = caps_v(false);
    __syncthreads();
    make_wv();
    __syncthreads();

    route(false, sp2);
    __threadfence();
    grid.sync();

    // ---- final squash -> out (q==0 blocks; out[b*512 + tid] == out[b][c][d])
    if (q == 0) {
#pragma unroll
        for (int m = 0; m < 2; m++) {
            const int o = tid + m * 512;
            float rr = 0.f;
#pragma unroll
            for (int k = 0; k < NQ; k++) rr += sp2[(size_t)(b * NQ + k) * (NC * IDIM) + o];
            scr[o] = rr;
        }
        __syncthreads();
        out[b * (NC * DC) + tid] = caps_v(false);
    }
}

extern "C" void kernel_launch(void* const* d_in, const int* in_sizes, int n_in,
                              void* d_out, int out_size, void* d_ws, size_t ws_size,
                              hipStream_t stream) {
    const float* x = (const float*)d_in[0];    // [64,1024,64]
    const float* W = (const float*)d_in[1];    // [16,64,32]
    float* out = (float*)d_out;                // [64,16,32]
    float* ws = (float*)d_ws;

    float* cs  = ws + WS_CS;
    float* sp1 = ws + WS_SP1;
    float* sp2 = ws + WS_SP2;

    void* args[] = {(void*)&x, (void*)&W, (void*)&out, (void*)&cs, (void*)&sp1, (void*)&sp2};
    hipLaunchCooperativeKernel((const void*)k_fused, dim3(B_SZ * NQ), dim3(NTHR),
                               args, 0, stream);
}

// Round 5
// 78.075 us; speedup vs baseline: 3.0713x; 3.0713x over previous
//
#include <hip/hip_runtime.h>
#include <math.h>

// Problem constants (fixed by reference setup_inputs)
#define B_SZ 64
#define N_IN 1024
#define IDIM 64
#define NC   16
#define DC   32

// Workspace layout (floats). NOTHING needs zero-init: every region is fully
// written before read (partials scheme, no atomics, no memset, no blog).
//  xsump : [64][8][64]       @ 0        colsum partials per 128-row chunk
//  sp1   : [64][16][16][64]  @ 32768    xs partials per 64-row chunk
//  sp2   : [64][16][16][64]  @ 1081344
//  wvT0  : [64][64][16]      @ 2129920  wv(v0), transposed [b][i][c]
//  wvT1  : [64][64][16]      @ 2195456  wv(v0)+wv(v1)  (logits are linear in wv)
#define WS_XSUMP 0
#define WS_SP1   32768
#define WS_SP2   1081344
#define WS_WVT0  2129920
#define WS_WVT1  2195456

// -------- Kernel 1: colsum partials xsump[b][chunk][i] = sum_{n in chunk} x[b,n,i]
__global__ __launch_bounds__(256) void k_colsum(const float* __restrict__ x,
                                                float* __restrict__ xsump) {
    const int b = blockIdx.y, chunk = blockIdx.x;          // 8 chunks of 128 rows
    const int i = threadIdx.x & 63, p = threadIdx.x >> 6;  // 4-way row split
    const float* xb = x + (size_t)(b * N_IN + chunk * 128) * IDIM;
    float s = 0.f;
    for (int r = p; r < 128; r += 4) s += xb[r * IDIM + i];  // coalesced 1KB/instr
    __shared__ float red[4][64];
    red[p][i] = s;
    __syncthreads();
    if (p == 0)
        xsump[(b * 8 + chunk) * 64 + i] = red[0][i] + red[1][i] + red[2][i] + red[3][i];
}

// -------- Kernel 2: capsule step, one block per batch (256 thr).
// MODE 0: red[i] from xsump (R=8), scale 1/16, write wvT0.
// MODE 1: red[c][i] from sp1 (R=16), write wvT1 = wv(v1) + wvT0.
// MODE 2: red[c][i] from sp2 (R=16), write output v.
template<int MODE>
__global__ __launch_bounds__(256) void k_caps(const float* __restrict__ partIn,
                                              const float* __restrict__ W,
                                              const float* __restrict__ wvPrev,
                                              float* __restrict__ outP) {
    const int b = blockIdx.x, tid = threadIdx.x;
    __shared__ float redSm[NC * 64];
    __shared__ float __align__(16) vSm[NC * DC];

    if (MODE == 0) {
        if (tid < 64) {
            float r = 0.f;
#pragma unroll
            for (int k = 0; k < 8; k++) r += partIn[(b * 8 + k) * 64 + tid];
            redSm[tid] = r;
        }
    } else {
#pragma unroll
        for (int m = 0; m < 4; m++) {
            const int o = tid + m * 256;
            float r = 0.f;
#pragma unroll
            for (int k = 0; k < 16; k++) r += partIn[((size_t)(b * 16 + k)) * 1024 + o];
            redSm[o] = r;
        }
    }
    __syncthreads();

    // s[c][d] for d = dp and dp+16;  thread = (c = tid>>4, dp = tid&15)
    const int c = tid >> 4, dp = tid & 15;
    const float* Wc = W + c * (IDIM * DC);
    float s0 = 0.f, s1 = 0.f;
#pragma unroll 8
    for (int i = 0; i < IDIM; i++) {
        const float rv = (MODE == 0) ? redSm[i] : redSm[c * 64 + i];
        s0 += rv * Wc[i * DC + dp];
        s1 += rv * Wc[i * DC + dp + 16];
    }
    if (MODE == 0) { s0 *= 0.0625f; s1 *= 0.0625f; }
    // squash: norm^2 over the 16-lane c-group (each lane holds 2 d's)
    float n2 = s0 * s0 + s1 * s1;
#pragma unroll
    for (int m = 8; m >= 1; m >>= 1) n2 += __shfl_xor(n2, m);
    const float nr = sqrtf(n2);
    const float g = (n2 / (1.f + n2)) / (nr + 1e-8f);
    if (MODE == 2) {
        outP[b * (NC * DC) + c * DC + dp]      = g * s0;
        outP[b * (NC * DC) + c * DC + dp + 16] = g * s1;
        return;
    }
    vSm[c * DC + dp]      = g * s0;
    vSm[c * DC + dp + 16] = g * s1;
    __syncthreads();

    // wvT[b][i][c2] = sum_d W[c2][i][d] * v[c2][d]   (+ wvPrev for MODE 1)
    const int i = tid & 63, cq = tid >> 6;
#pragma unroll
    for (int h = 0; h < 4; h++) {
        const int c2 = h * 4 + cq;                       // wave-uniform
        const float4* Wr = reinterpret_cast<const float4*>(W + (size_t)(c2 * IDIM + i) * DC);
        const float4* vv = reinterpret_cast<const float4*>(vSm + c2 * DC);
        float acc = 0.f;
#pragma unroll
        for (int dq = 0; dq < 8; dq++) {
            const float4 wq = Wr[dq];
            const float4 vq = vv[dq];                    // LDS broadcast
            acc += wq.x * vq.x + wq.y * vq.y + wq.z * vq.z + wq.w * vq.w;
        }
        const size_t oidx = ((size_t)b * IDIM + i) * NC + c2;
        outP[oidx] = acc + ((MODE == 1) ? wvPrev[oidx] : 0.f);
    }
}

// -------- Kernel 3: routing pass. Per (b, 64-row chunk), 256 thr = 4 waves.
// logits a[c][n] = x[n] . wvEff[c]; softmax over c; xs partial out (no blog:
// for iter 2, wvEff = wv(v0)+wv(v1) so a = b2 directly).
__global__ __launch_bounds__(256, 4) void k_route(const float* __restrict__ x,
                                                  const float* __restrict__ wvT,
                                                  float* __restrict__ sp) {
    const int b = blockIdx.y, chunk = blockIdx.x;   // 16 chunks of 64 rows
    const int tid = threadIdx.x, lane = tid & 63, wave = tid >> 6;

    __shared__ float xT[IDIM * 64];                 // 16 KB skewed: (n,i) -> xT[i*64+((n+i)&63)]
    __shared__ float __align__(16) wSm[64 * NC];    // transposed [i][c]
    __shared__ float aSm[NC * 64];                  // [c][n]
    __shared__ float __align__(16) cwT[64 * NC];    // transposed [n][c]

    // load x chunk (4 float4/thread) + wv (1 float4/thread)
    const float4* xb4 = reinterpret_cast<const float4*>(x + ((size_t)b * N_IN + chunk * 64) * IDIM);
    float4 xr[4];
#pragma unroll
    for (int m = 0; m < 4; m++) xr[m] = xb4[tid + m * 256];
    reinterpret_cast<float4*>(wSm)[tid] =
        reinterpret_cast<const float4*>(wvT + (size_t)b * (IDIM * NC))[tid];
#pragma unroll
    for (int m = 0; m < 4; m++) {
        const int f = tid + m * 256, np = f >> 4, i0 = (f & 15) * 4;
        const float vv[4] = {xr[m].x, xr[m].y, xr[m].z, xr[m].w};
#pragma unroll
        for (int j = 0; j < 4; j++) {
            const int i = i0 + j;
            xT[i * 64 + ((np + i) & 63)] = vv[j];
        }
    }
    __syncthreads();

    // agreement: wave w -> caps c0..c0+3, lane = row n'
    const int c0 = wave * 4;
    float a4[4] = {0.f, 0.f, 0.f, 0.f};
#pragma unroll 8
    for (int i = 0; i < IDIM; i++) {
        const float xv = xT[i * 64 + ((lane + i) & 63)];
        const float4 w4 = *reinterpret_cast<const float4*>(&wSm[i * NC + c0]);  // broadcast
        a4[0] += xv * w4.x; a4[1] += xv * w4.y; a4[2] += xv * w4.z; a4[3] += xv * w4.w;
    }
#pragma unroll
    for (int cc = 0; cc < 4; cc++) aSm[(c0 + cc) * 64 + lane] = a4[cc];
    __syncthreads();

    // softmax over 16 caps per row (rotated so av[0..3] are this wave's caps)
    float av[NC];
#pragma unroll
    for (int k = 0; k < NC; k++) av[k] = aSm[((k + c0) & 15) * 64 + lane];
    float mx = av[0];
#pragma unroll
    for (int k = 1; k < NC; k++) mx = fmaxf(mx, av[k]);
    float ssum = 0.f;
#pragma unroll
    for (int k = 0; k < NC; k++) { av[k] = __expf(av[k] - mx); ssum += av[k]; }
    const float inv = 1.f / ssum;
    float4 cw4;
    cw4.x = av[0] * inv; cw4.y = av[1] * inv; cw4.z = av[2] * inv; cw4.w = av[3] * inv;
    *reinterpret_cast<float4*>(&cwT[lane * NC + c0]) = cw4;   // one-time b128 write
    __syncthreads();

    // xs partial: wave w covers all 64 rows for caps c0..c0+3; lane = i
    float o4[4] = {0.f, 0.f, 0.f, 0.f};
#pragma unroll 8
    for (int nl = 0; nl < 64; nl++) {
        const float xv = xT[lane * 64 + ((nl + lane) & 63)];
        const float4 c4 = *reinterpret_cast<const float4*>(&cwT[nl * NC + c0]);  // broadcast
        o4[0] += xv * c4.x; o4[1] += xv * c4.y; o4[2] += xv * c4.z; o4[3] += xv * c4.w;
    }
    float* spq = sp + (size_t)(b * 16 + chunk) * 1024;
#pragma unroll
    for (int cc = 0; cc < 4; cc++) spq[(c0 + cc) * 64 + lane] = o4[cc];
}

extern "C" void kernel_launch(void* const* d_in, const int* in_sizes, int n_in,
                              void* d_out, int out_size, void* d_ws, size_t ws_size,
                              hipStream_t stream) {
    const float* x = (const float*)d_in[0];    // [64,1024,64]
    const float* W = (const float*)d_in[1];    // [16,64,32]
    float* out = (float*)d_out;                // [64,16,32]
    float* ws = (float*)d_ws;

    float* xsump = ws + WS_XSUMP;
    float* sp1   = ws + WS_SP1;
    float* sp2   = ws + WS_SP2;
    float* wvT0  = ws + WS_WVT0;
    float* wvT1  = ws + WS_WVT1;

    // iter 0: colsum -> v0 -> wvT0
    k_colsum<<<dim3(8, B_SZ), 256, 0, stream>>>(x, xsump);
    k_caps<0><<<B_SZ, 256, 0, stream>>>(xsump, W, wvT0, wvT0);
    // iter 1: logits = x.wv0 -> softmax -> sp1
    k_route<<<dim3(16, B_SZ), 256, 0, stream>>>(x, wvT0, sp1);
    // v1 from sp1; wvT1 = wv(v1) + wvT0  (so next logits = b1 + a1 = b2)
    k_caps<1><<<B_SZ, 256, 0, stream>>>(sp1, W, wvT0, wvT1);
    // iter 2: logits = x.(wv0+wv1) = b2 -> softmax -> sp2
    k_route<<<dim3(16, B_SZ), 256, 0, stream>>>(x, wvT1, sp2);
    // final squash -> out
    k_caps<2><<<B_SZ, 256, 0, stream>>>(sp2, W, wvT1, out);
}